// Round 1
// baseline (230.679 us; speedup 1.0000x reference)
//
#include <hip/hip_runtime.h>
#include <hip/hip_bf16.h>

#define D 128          // D_IN == D_OUT == 128
#define NPW 4          // nodes per wave in fused kernel
#define EPS 1e-8f

// ---------------- CSR build ----------------

__global__ void k_hist(const int* __restrict__ ei, int* __restrict__ deg, int E_) {
    int e = blockIdx.x * blockDim.x + threadIdx.x;
    if (e < E_) atomicAdd(&deg[ei[e]], 1);   // ei[e] = row (destination)
}

__global__ void k_scan(const int* __restrict__ deg, int* __restrict__ row_start, int N_) {
    __shared__ int part[256];
    int t = threadIdx.x;
    int chunk = (N_ + 255) / 256;
    int s = t * chunk;
    int e = min(N_, s + chunk);
    int sum = 0;
    for (int i = s; i < e; ++i) sum += deg[i];
    part[t] = sum;
    __syncthreads();
    // inclusive scan (Hillis-Steele, barrier-safe read-then-write)
    for (int off = 1; off < 256; off <<= 1) {
        int u = (t >= off) ? part[t - off] : 0;
        __syncthreads();
        part[t] += u;
        __syncthreads();
    }
    int run = part[t] - sum;   // exclusive prefix of this thread's chunk
    for (int i = s; i < e; ++i) { row_start[i] = run; run += deg[i]; }
    if (t == 255) row_start[N_] = part[255];
}

__global__ void k_place(const int* __restrict__ ei, const int* __restrict__ row_start,
                        int* __restrict__ cursor, int* __restrict__ csr_col, int E_) {
    int e = blockIdx.x * blockDim.x + threadIdx.x;
    if (e < E_) {
        int r = ei[e];
        int c = ei[E_ + e];
        int pos = row_start[r] + atomicAdd(&cursor[r], 1);
        csr_col[pos] = c;
    }
}

// ---------------- fused aggregate + 2x matvec + norm ----------------
// block = 256 threads = 4 waves; each wave owns NPW consecutive nodes.
// Per node: agg = sum_{e in CSR row} x[col[e]]  (f32x2 per lane)
//           out1 = (agg @ Wm^T + deg*bm) / (deg+eps)
//           out2 = out1 @ Wu^T + bu
//           out  = out2 / (||out2|| + eps)

__global__ __launch_bounds__(256) void k_fused(
        const float* __restrict__ x,
        const int* __restrict__ row_start, const int* __restrict__ csr_col,
        const float* __restrict__ Wm, const float* __restrict__ bm,
        const float* __restrict__ Wu, const float* __restrict__ bu,
        float* __restrict__ out, int N_) {
    __shared__ float a_lds[4 * NPW][D];   // aggregated rows
    __shared__ float o_lds[4 * NPW][D];   // out1 rows

    const int lane = threadIdx.x & 63;
    const int wv   = threadIdx.x >> 6;
    const int nbase = blockIdx.x * (4 * NPW) + wv * NPW;

    const float2* __restrict__ x2 = (const float2*)x;

    int deg_[NPW];
    #pragma unroll
    for (int i = 0; i < NPW; ++i) {
        int n = nbase + i;
        int s = 0, e = 0;
        if (n < N_) { s = row_start[n]; e = row_start[n + 1]; }
        deg_[i] = e - s;
        float2 acc = make_float2(0.f, 0.f);
        for (int ii = s; ii < e; ii += 64) {
            int c_l = 0;
            if (ii + lane < e) c_l = csr_col[ii + lane];
            int m = min(64, e - ii);
            for (int t = 0; t < m; ++t) {
                int c = __shfl(c_l, t);
                float2 xr = x2[c * (D / 2) + lane];
                acc.x += xr.x;
                acc.y += xr.y;
            }
        }
        int nl = wv * NPW + i;
        a_lds[nl][2 * lane]     = acc.x;
        a_lds[nl][2 * lane + 1] = acc.y;
    }
    __syncthreads();

    const int f0 = lane, f1 = lane + 64;

    // ---- matvec 1: out1 = (agg @ Wm^T + deg*bm) * inv ----
    float acc0[NPW], acc1[NPW];
    #pragma unroll
    for (int i = 0; i < NPW; ++i) { acc0[i] = 0.f; acc1[i] = 0.f; }

    for (int k0 = 0; k0 < D; k0 += 4) {
        float4 w0 = *(const float4*)&Wm[f0 * D + k0];
        float4 w1 = *(const float4*)&Wm[f1 * D + k0];
        #pragma unroll
        for (int i = 0; i < NPW; ++i) {
            float4 a4 = *(const float4*)&a_lds[wv * NPW + i][k0];
            acc0[i] += a4.x * w0.x + a4.y * w0.y + a4.z * w0.z + a4.w * w0.w;
            acc1[i] += a4.x * w1.x + a4.y * w1.y + a4.z * w1.z + a4.w * w1.w;
        }
    }

    float bm0 = bm[f0], bm1 = bm[f1];
    #pragma unroll
    for (int i = 0; i < NPW; ++i) {
        float cnt = (float)deg_[i];
        float inv = 1.0f / (cnt + EPS);
        int nl = wv * NPW + i;
        o_lds[nl][f0] = (acc0[i] + cnt * bm0) * inv;
        o_lds[nl][f1] = (acc1[i] + cnt * bm1) * inv;
    }
    __syncthreads();

    // ---- matvec 2: out2 = out1 @ Wu^T + bu ----
    #pragma unroll
    for (int i = 0; i < NPW; ++i) { acc0[i] = 0.f; acc1[i] = 0.f; }

    for (int k0 = 0; k0 < D; k0 += 4) {
        float4 w0 = *(const float4*)&Wu[f0 * D + k0];
        float4 w1 = *(const float4*)&Wu[f1 * D + k0];
        #pragma unroll
        for (int i = 0; i < NPW; ++i) {
            float4 a4 = *(const float4*)&o_lds[wv * NPW + i][k0];
            acc0[i] += a4.x * w0.x + a4.y * w0.y + a4.z * w0.z + a4.w * w0.w;
            acc1[i] += a4.x * w1.x + a4.y * w1.y + a4.z * w1.z + a4.w * w1.w;
        }
    }

    float bu0 = bu[f0], bu1 = bu[f1];
    #pragma unroll
    for (int i = 0; i < NPW; ++i) {
        int n = nbase + i;
        if (n >= N_) continue;
        float t0 = acc0[i] + bu0;
        float t1 = acc1[i] + bu1;
        float v = t0 * t0 + t1 * t1;
        #pragma unroll
        for (int off = 32; off > 0; off >>= 1) v += __shfl_xor(v, off);
        float scale = 1.0f / (sqrtf(v) + EPS);
        out[n * D + f0] = t0 * scale;
        out[n * D + f1] = t1 * scale;
    }
}

// ---------------- launch ----------------

extern "C" void kernel_launch(void* const* d_in, const int* in_sizes, int n_in,
                              void* d_out, int out_size, void* d_ws, size_t ws_size,
                              hipStream_t stream) {
    const float* x  = (const float*)d_in[0];
    const int*   ei = (const int*)d_in[1];
    const float* Wm = (const float*)d_in[2];
    const float* bm = (const float*)d_in[3];
    const float* Wu = (const float*)d_in[4];
    const float* bu = (const float*)d_in[5];
    float* out = (float*)d_out;

    const int N_ = in_sizes[0] / D;     // 10000
    const int E_ = in_sizes[1] / 2;     // 640000

    int* deg       = (int*)d_ws;            // N
    int* cursor    = deg + N_;               // N
    int* row_start = cursor + N_;            // N+1
    int* csr_col   = row_start + (N_ + 1);   // E

    hipMemsetAsync(deg, 0, 2 * (size_t)N_ * sizeof(int), stream);

    k_hist<<<(E_ + 255) / 256, 256, 0, stream>>>(ei, deg, E_);
    k_scan<<<1, 256, 0, stream>>>(deg, row_start, N_);
    k_place<<<(E_ + 255) / 256, 256, 0, stream>>>(ei, row_start, cursor, csr_col, E_);

    int nodes_per_block = 4 * NPW;  // 16
    k_fused<<<(N_ + nodes_per_block - 1) / nodes_per_block, 256, 0, stream>>>(
        x, row_start, csr_col, Wm, bm, Wu, bu, out, N_);
}

// Round 2
// 183.940 us; speedup vs baseline: 1.2541x; 1.2541x over previous
//
#include <hip/hip_runtime.h>
#include <hip/hip_bf16.h>

#define D 128          // D_IN == D_OUT == 128
#define NPW 4          // nodes per wave in update kernel
#define EPS 1e-8f

typedef unsigned int uint32;

// ---------------- prep: bf16-convert x + degree histogram ----------------

__device__ __forceinline__ uint32 f2bf_rne(float f) {
    uint32 u = __float_as_uint(f);
    return (u + 0x7fffu + ((u >> 16) & 1u)) >> 16;   // round-nearest-even
}

__global__ void k_prep(const float* __restrict__ x, const int* __restrict__ ei,
                       uint32* __restrict__ xb, int* __restrict__ deg,
                       int E_, int NX) {
    int i = blockIdx.x * blockDim.x + threadIdx.x;
    if (i < E_) atomicAdd(&deg[ei[i]], 1);           // ei[i] = row (destination)
    if (i < NX) {
        float2 f = ((const float2*)x)[i];
        xb[i] = f2bf_rne(f.x) | (f2bf_rne(f.y) << 16);
    }
}

// ---------------- scan ----------------

__global__ void k_scan(const int* __restrict__ deg, int* __restrict__ row_start, int N_) {
    __shared__ int part[256];
    int t = threadIdx.x;
    int chunk = (N_ + 255) / 256;
    int s = t * chunk;
    int e = min(N_, s + chunk);
    int sum = 0;
    for (int i = s; i < e; ++i) sum += deg[i];
    part[t] = sum;
    __syncthreads();
    for (int off = 1; off < 256; off <<= 1) {
        int u = (t >= off) ? part[t - off] : 0;
        __syncthreads();
        part[t] += u;
        __syncthreads();
    }
    int run = part[t] - sum;
    for (int i = s; i < e; ++i) { row_start[i] = run; run += deg[i]; }
    if (t == 255) row_start[N_] = part[255];
}

// ---------------- place ----------------

__global__ void k_place(const int* __restrict__ ei, const int* __restrict__ row_start,
                        int* __restrict__ cursor, int* __restrict__ csr_col, int E_) {
    int e = blockIdx.x * blockDim.x + threadIdx.x;
    if (e < E_) {
        int r = ei[e];
        int c = ei[E_ + e];
        int pos = row_start[r] + atomicAdd(&cursor[r], 1);
        csr_col[pos] = c;
    }
}

// ---------------- gather: one wave per node, bf16 rows, readlane bcast ----
// agg[n][lane] = float2 sum of x[col] rows (features 2*lane, 2*lane+1)

__global__ __launch_bounds__(256) void k_gather(
        const uint32* __restrict__ xb, const int* __restrict__ row_start,
        const int* __restrict__ csr_col, float2* __restrict__ agg, int N_) {
    const int lane = threadIdx.x & 63;
    const int wv   = threadIdx.x >> 6;
    const int n    = blockIdx.x * 4 + wv;
    if (n >= N_) return;

    int s = row_start[n];
    int e = row_start[n + 1];

    float ax0 = 0.f, ay0 = 0.f, ax1 = 0.f, ay1 = 0.f;

    int ii = s;
    for (; ii + 64 <= e; ii += 64) {
        int c_l = csr_col[ii + lane];
        #pragma unroll
        for (int t = 0; t < 64; t += 8) {
            int c0 = __builtin_amdgcn_readlane(c_l, t + 0);
            int c1 = __builtin_amdgcn_readlane(c_l, t + 1);
            int c2 = __builtin_amdgcn_readlane(c_l, t + 2);
            int c3 = __builtin_amdgcn_readlane(c_l, t + 3);
            int c4 = __builtin_amdgcn_readlane(c_l, t + 4);
            int c5 = __builtin_amdgcn_readlane(c_l, t + 5);
            int c6 = __builtin_amdgcn_readlane(c_l, t + 6);
            int c7 = __builtin_amdgcn_readlane(c_l, t + 7);
            uint32 v0 = xb[(c0 << 6) + lane];
            uint32 v1 = xb[(c1 << 6) + lane];
            uint32 v2 = xb[(c2 << 6) + lane];
            uint32 v3 = xb[(c3 << 6) + lane];
            uint32 v4 = xb[(c4 << 6) + lane];
            uint32 v5 = xb[(c5 << 6) + lane];
            uint32 v6 = xb[(c6 << 6) + lane];
            uint32 v7 = xb[(c7 << 6) + lane];
            ax0 += __uint_as_float(v0 << 16); ay0 += __uint_as_float(v0 & 0xffff0000u);
            ax1 += __uint_as_float(v1 << 16); ay1 += __uint_as_float(v1 & 0xffff0000u);
            ax0 += __uint_as_float(v2 << 16); ay0 += __uint_as_float(v2 & 0xffff0000u);
            ax1 += __uint_as_float(v3 << 16); ay1 += __uint_as_float(v3 & 0xffff0000u);
            ax0 += __uint_as_float(v4 << 16); ay0 += __uint_as_float(v4 & 0xffff0000u);
            ax1 += __uint_as_float(v5 << 16); ay1 += __uint_as_float(v5 & 0xffff0000u);
            ax0 += __uint_as_float(v6 << 16); ay0 += __uint_as_float(v6 & 0xffff0000u);
            ax1 += __uint_as_float(v7 << 16); ay1 += __uint_as_float(v7 & 0xffff0000u);
        }
    }
    int m = e - ii;
    if (m > 0) {
        int c_l = (lane < m) ? csr_col[ii + lane] : 0;
        for (int t = 0; t < m; ++t) {
            int c = __builtin_amdgcn_readlane(c_l, t);
            uint32 v = xb[(c << 6) + lane];
            ax0 += __uint_as_float(v << 16);
            ay0 += __uint_as_float(v & 0xffff0000u);
        }
    }
    agg[(n << 6) + lane] = make_float2(ax0 + ax1, ay0 + ay1);
}

// ---------------- update: 2x matvec + mean + norm ----------------
// block = 256 = 4 waves; each wave owns NPW nodes.

__global__ __launch_bounds__(256) void k_update(
        const float2* __restrict__ agg, const int* __restrict__ row_start,
        const float* __restrict__ Wm, const float* __restrict__ bm,
        const float* __restrict__ Wu, const float* __restrict__ bu,
        float* __restrict__ out, int N_) {
    __shared__ float a_lds[4 * NPW][D];
    __shared__ float o_lds[4 * NPW][D];

    const int lane = threadIdx.x & 63;
    const int wv   = threadIdx.x >> 6;
    const int nbase = blockIdx.x * (4 * NPW) + wv * NPW;

    int deg_[NPW];
    #pragma unroll
    for (int i = 0; i < NPW; ++i) {
        int n = nbase + i;
        int nl = wv * NPW + i;
        float2 v = make_float2(0.f, 0.f);
        deg_[i] = 0;
        if (n < N_) {
            deg_[i] = row_start[n + 1] - row_start[n];
            v = agg[(n << 6) + lane];
        }
        a_lds[nl][2 * lane]     = v.x;
        a_lds[nl][2 * lane + 1] = v.y;
    }
    __syncthreads();

    const int f0 = lane, f1 = lane + 64;

    // ---- matvec 1: out1 = (agg @ Wm^T + deg*bm) / (deg+eps) ----
    float acc0[NPW], acc1[NPW];
    #pragma unroll
    for (int i = 0; i < NPW; ++i) { acc0[i] = 0.f; acc1[i] = 0.f; }

    for (int k0 = 0; k0 < D; k0 += 4) {
        float4 w0 = *(const float4*)&Wm[f0 * D + k0];
        float4 w1 = *(const float4*)&Wm[f1 * D + k0];
        #pragma unroll
        for (int i = 0; i < NPW; ++i) {
            float4 a4 = *(const float4*)&a_lds[wv * NPW + i][k0];
            acc0[i] += a4.x * w0.x + a4.y * w0.y + a4.z * w0.z + a4.w * w0.w;
            acc1[i] += a4.x * w1.x + a4.y * w1.y + a4.z * w1.z + a4.w * w1.w;
        }
    }

    float bm0 = bm[f0], bm1 = bm[f1];
    #pragma unroll
    for (int i = 0; i < NPW; ++i) {
        float cnt = (float)deg_[i];
        float inv = 1.0f / (cnt + EPS);
        int nl = wv * NPW + i;
        o_lds[nl][f0] = (acc0[i] + cnt * bm0) * inv;
        o_lds[nl][f1] = (acc1[i] + cnt * bm1) * inv;
    }
    __syncthreads();

    // ---- matvec 2: out2 = out1 @ Wu^T + bu ----
    #pragma unroll
    for (int i = 0; i < NPW; ++i) { acc0[i] = 0.f; acc1[i] = 0.f; }

    for (int k0 = 0; k0 < D; k0 += 4) {
        float4 w0 = *(const float4*)&Wu[f0 * D + k0];
        float4 w1 = *(const float4*)&Wu[f1 * D + k0];
        #pragma unroll
        for (int i = 0; i < NPW; ++i) {
            float4 a4 = *(const float4*)&o_lds[wv * NPW + i][k0];
            acc0[i] += a4.x * w0.x + a4.y * w0.y + a4.z * w0.z + a4.w * w0.w;
            acc1[i] += a4.x * w1.x + a4.y * w1.y + a4.z * w1.z + a4.w * w1.w;
        }
    }

    float bu0 = bu[f0], bu1 = bu[f1];
    #pragma unroll
    for (int i = 0; i < NPW; ++i) {
        int n = nbase + i;
        if (n >= N_) continue;
        float t0 = acc0[i] + bu0;
        float t1 = acc1[i] + bu1;
        float v = t0 * t0 + t1 * t1;
        #pragma unroll
        for (int off = 32; off > 0; off >>= 1) v += __shfl_xor(v, off);
        float scale = 1.0f / (sqrtf(v) + EPS);
        out[n * D + f0] = t0 * scale;
        out[n * D + f1] = t1 * scale;
    }
}

// ---------------- launch ----------------

extern "C" void kernel_launch(void* const* d_in, const int* in_sizes, int n_in,
                              void* d_out, int out_size, void* d_ws, size_t ws_size,
                              hipStream_t stream) {
    const float* x  = (const float*)d_in[0];
    const int*   ei = (const int*)d_in[1];
    const float* Wm = (const float*)d_in[2];
    const float* bm = (const float*)d_in[3];
    const float* Wu = (const float*)d_in[4];
    const float* bu = (const float*)d_in[5];
    float* out = (float*)d_out;

    const int N_ = in_sizes[0] / D;     // 10000
    const int E_ = in_sizes[1] / 2;     // 640000
    const int NX = N_ * (D / 2);        // 640000 packed pairs

    int* deg       = (int*)d_ws;                  // N
    int* cursor    = deg + N_;                    // N
    int* row_start = cursor + N_;                 // N+1
    int* csr_col   = row_start + (N_ + 1);        // E
    uint32* xb     = (uint32*)(csr_col + E_);     // N*64
    float2* agg    = (float2*)(xb + NX);          // N*64 float2

    hipMemsetAsync(deg, 0, 2 * (size_t)N_ * sizeof(int), stream);

    int pgrid = (max(E_, NX) + 255) / 256;
    k_prep<<<pgrid, 256, 0, stream>>>(x, ei, xb, deg, E_, NX);
    k_scan<<<1, 256, 0, stream>>>(deg, row_start, N_);
    k_place<<<(E_ + 255) / 256, 256, 0, stream>>>(ei, row_start, cursor, csr_col, E_);

    k_gather<<<(N_ + 3) / 4, 256, 0, stream>>>(xb, row_start, csr_col, agg, N_);

    k_update<<<(N_ + 4 * NPW - 1) / (4 * NPW), 256, 0, stream>>>(
        agg, row_start, Wm, bm, Wu, bu, out, N_);
}

// Round 3
// 148.946 us; speedup vs baseline: 1.5487x; 1.2349x over previous
//
#include <hip/hip_runtime.h>
#include <hip/hip_bf16.h>

#define D 128          // D_IN == D_OUT == 128
#define NPW 4          // nodes per wave in update kernel
#define EPS 1e-8f

typedef unsigned int uint32;

__device__ __forceinline__ uint32 f2bf_rne(float f) {
    uint32 u = __float_as_uint(f);
    return (u + 0x7fffu + ((u >> 16) & 1u)) >> 16;   // round-nearest-even
}
__device__ __forceinline__ float bfl(uint32 u) { return __uint_as_float(u << 16); }
__device__ __forceinline__ float bfh(uint32 u) { return __uint_as_float(u & 0xffff0000u); }

// ---------------- prep: bf16-convert x + degree histogram ----------------

__global__ void k_prep(const float* __restrict__ x, const int* __restrict__ ei,
                       uint32* __restrict__ xb, int* __restrict__ deg,
                       int E_, int NX) {
    int i = blockIdx.x * blockDim.x + threadIdx.x;
    if (i < E_) atomicAdd(&deg[ei[i]], 1);           // ei[i] = row (destination)
    if (i < NX) {
        float2 f = ((const float2*)x)[i];
        xb[i] = f2bf_rne(f.x) | (f2bf_rne(f.y) << 16);
    }
}

// ---------------- W transpose + bf16 pack: WT[k2][f] = {W[f][2k2], W[f][2k2+1]} ----

__global__ void k_wprep(const float* __restrict__ Wm, const float* __restrict__ Wu,
                        uint32* __restrict__ WTmb, uint32* __restrict__ WTub) {
    int i = blockIdx.x * blockDim.x + threadIdx.x;   // 64*128 threads
    if (i >= 64 * 128) return;
    int k2 = i >> 7, f = i & 127;
    WTmb[i] = f2bf_rne(Wm[f * D + 2 * k2]) | (f2bf_rne(Wm[f * D + 2 * k2 + 1]) << 16);
    WTub[i] = f2bf_rne(Wu[f * D + 2 * k2]) | (f2bf_rne(Wu[f * D + 2 * k2 + 1]) << 16);
}

// ---------------- scan ----------------

__global__ void k_scan(const int* __restrict__ deg, int* __restrict__ row_start, int N_) {
    __shared__ int part[1024];
    int t = threadIdx.x;
    int chunk = (N_ + 1023) / 1024;
    int s = t * chunk;
    int e = min(N_, s + chunk);
    int sum = 0;
    for (int i = s; i < e; ++i) sum += deg[i];
    part[t] = sum;
    __syncthreads();
    for (int off = 1; off < 1024; off <<= 1) {
        int u = (t >= off) ? part[t - off] : 0;
        __syncthreads();
        part[t] += u;
        __syncthreads();
    }
    int run = part[t] - sum;
    for (int i = s; i < e; ++i) { row_start[i] = run; run += deg[i]; }
    if (t == 1023) row_start[N_] = part[1023];
}

// ---------------- place ----------------

__global__ void k_place(const int* __restrict__ ei, const int* __restrict__ row_start,
                        int* __restrict__ cursor, int* __restrict__ csr_col, int E_) {
    int e = blockIdx.x * blockDim.x + threadIdx.x;
    if (e < E_) {
        int r = ei[e];
        int c = ei[E_ + e];
        int pos = row_start[r] + atomicAdd(&cursor[r], 1);
        csr_col[pos] = c;
    }
}

// ---------------- gather: 2 waves per node, halves combined via LDS ----------

__global__ __launch_bounds__(256) void k_gather(
        const uint32* __restrict__ xb, const int* __restrict__ row_start,
        const int* __restrict__ csr_col, float2* __restrict__ agg, int N_) {
    __shared__ float2 part[4][64];
    const int lane = threadIdx.x & 63;
    const int wv   = threadIdx.x >> 6;
    const int n    = blockIdx.x * 2 + (wv >> 1);
    const int half = wv & 1;

    int s = 0, e = 0;
    if (n < N_) { s = row_start[n]; e = row_start[n + 1]; }
    int mid = s + ((e - s + 1) >> 1);
    int lo = half ? mid : s;
    int hi = half ? e : mid;

    float ax0 = 0.f, ay0 = 0.f, ax1 = 0.f, ay1 = 0.f;

    for (int ii = lo; ii < hi; ii += 64) {
        int m = min(64, hi - ii);
        int c_l = (lane < m) ? csr_col[ii + lane] : 0;
        int t = 0;
        for (; t + 8 <= m; t += 8) {
            int c0 = __builtin_amdgcn_readlane(c_l, t + 0);
            int c1 = __builtin_amdgcn_readlane(c_l, t + 1);
            int c2 = __builtin_amdgcn_readlane(c_l, t + 2);
            int c3 = __builtin_amdgcn_readlane(c_l, t + 3);
            int c4 = __builtin_amdgcn_readlane(c_l, t + 4);
            int c5 = __builtin_amdgcn_readlane(c_l, t + 5);
            int c6 = __builtin_amdgcn_readlane(c_l, t + 6);
            int c7 = __builtin_amdgcn_readlane(c_l, t + 7);
            uint32 v0 = xb[(c0 << 6) + lane];
            uint32 v1 = xb[(c1 << 6) + lane];
            uint32 v2 = xb[(c2 << 6) + lane];
            uint32 v3 = xb[(c3 << 6) + lane];
            uint32 v4 = xb[(c4 << 6) + lane];
            uint32 v5 = xb[(c5 << 6) + lane];
            uint32 v6 = xb[(c6 << 6) + lane];
            uint32 v7 = xb[(c7 << 6) + lane];
            ax0 += bfl(v0); ay0 += bfh(v0);
            ax1 += bfl(v1); ay1 += bfh(v1);
            ax0 += bfl(v2); ay0 += bfh(v2);
            ax1 += bfl(v3); ay1 += bfh(v3);
            ax0 += bfl(v4); ay0 += bfh(v4);
            ax1 += bfl(v5); ay1 += bfh(v5);
            ax0 += bfl(v6); ay0 += bfh(v6);
            ax1 += bfl(v7); ay1 += bfh(v7);
        }
        for (; t < m; ++t) {
            int c = __builtin_amdgcn_readlane(c_l, t);
            uint32 v = xb[(c << 6) + lane];
            ax0 += bfl(v); ay0 += bfh(v);
        }
    }
    part[wv][lane] = make_float2(ax0 + ax1, ay0 + ay1);
    __syncthreads();
    if (half == 0 && n < N_) {
        float2 a = part[wv][lane];
        float2 b = part[wv + 1][lane];
        agg[(n << 6) + lane] = make_float2(a.x + b.x, a.y + b.y);
    }
}

// ---------------- update: 2x matvec (coalesced bf16 W^T) + mean + norm -------

__global__ __launch_bounds__(256) void k_update(
        const float2* __restrict__ agg, const int* __restrict__ row_start,
        const uint32* __restrict__ WTmb, const float* __restrict__ bm,
        const uint32* __restrict__ WTub, const float* __restrict__ bu,
        float* __restrict__ out, int N_) {
    __shared__ float a_lds[4 * NPW][D];
    __shared__ float o_lds[4 * NPW][D];

    const int lane = threadIdx.x & 63;
    const int wv   = threadIdx.x >> 6;
    const int nbase = blockIdx.x * (4 * NPW) + wv * NPW;

    int deg_[NPW];
    #pragma unroll
    for (int i = 0; i < NPW; ++i) {
        int n = nbase + i;
        int nl = wv * NPW + i;
        float2 v = make_float2(0.f, 0.f);
        deg_[i] = 0;
        if (n < N_) {
            deg_[i] = row_start[n + 1] - row_start[n];
            v = agg[(n << 6) + lane];
        }
        a_lds[nl][2 * lane]     = v.x;
        a_lds[nl][2 * lane + 1] = v.y;
    }
    __syncthreads();

    const int f0 = lane, f1 = lane + 64;

    // ---- matvec 1: out1 = (agg @ Wm^T + deg*bm) / (deg+eps) ----
    float acc0[NPW], acc1[NPW];
    #pragma unroll
    for (int i = 0; i < NPW; ++i) { acc0[i] = 0.f; acc1[i] = 0.f; }

    for (int k2 = 0; k2 < 64; k2 += 2) {
        uint32 wm00 = WTmb[k2 * D + f0];
        uint32 wm01 = WTmb[(k2 + 1) * D + f0];
        uint32 wm10 = WTmb[k2 * D + f1];
        uint32 wm11 = WTmb[(k2 + 1) * D + f1];
        float w00l = bfl(wm00), w00h = bfh(wm00), w01l = bfl(wm01), w01h = bfh(wm01);
        float w10l = bfl(wm10), w10h = bfh(wm10), w11l = bfl(wm11), w11h = bfh(wm11);
        #pragma unroll
        for (int i = 0; i < NPW; ++i) {
            float4 a4 = *(const float4*)&a_lds[wv * NPW + i][2 * k2];
            acc0[i] += a4.x * w00l + a4.y * w00h + a4.z * w01l + a4.w * w01h;
            acc1[i] += a4.x * w10l + a4.y * w10h + a4.z * w11l + a4.w * w11h;
        }
    }

    float bm0 = bm[f0], bm1 = bm[f1];
    #pragma unroll
    for (int i = 0; i < NPW; ++i) {
        float cnt = (float)deg_[i];
        float inv = 1.0f / (cnt + EPS);
        int nl = wv * NPW + i;
        o_lds[nl][f0] = (acc0[i] + cnt * bm0) * inv;
        o_lds[nl][f1] = (acc1[i] + cnt * bm1) * inv;
    }
    __syncthreads();

    // ---- matvec 2: out2 = out1 @ Wu^T + bu ----
    #pragma unroll
    for (int i = 0; i < NPW; ++i) { acc0[i] = 0.f; acc1[i] = 0.f; }

    for (int k2 = 0; k2 < 64; k2 += 2) {
        uint32 wu00 = WTub[k2 * D + f0];
        uint32 wu01 = WTub[(k2 + 1) * D + f0];
        uint32 wu10 = WTub[k2 * D + f1];
        uint32 wu11 = WTub[(k2 + 1) * D + f1];
        float w00l = bfl(wu00), w00h = bfh(wu00), w01l = bfl(wu01), w01h = bfh(wu01);
        float w10l = bfl(wu10), w10h = bfh(wu10), w11l = bfl(wu11), w11h = bfh(wu11);
        #pragma unroll
        for (int i = 0; i < NPW; ++i) {
            float4 a4 = *(const float4*)&o_lds[wv * NPW + i][2 * k2];
            acc0[i] += a4.x * w00l + a4.y * w00h + a4.z * w01l + a4.w * w01h;
            acc1[i] += a4.x * w10l + a4.y * w10h + a4.z * w11l + a4.w * w11h;
        }
    }

    float bu0 = bu[f0], bu1 = bu[f1];
    #pragma unroll
    for (int i = 0; i < NPW; ++i) {
        int n = nbase + i;
        if (n >= N_) continue;
        float t0 = acc0[i] + bu0;
        float t1 = acc1[i] + bu1;
        float v = t0 * t0 + t1 * t1;
        #pragma unroll
        for (int off = 32; off > 0; off >>= 1) v += __shfl_xor(v, off);
        float scale = 1.0f / (sqrtf(v) + EPS);
        out[n * D + f0] = t0 * scale;
        out[n * D + f1] = t1 * scale;
    }
}

// ---------------- launch ----------------

extern "C" void kernel_launch(void* const* d_in, const int* in_sizes, int n_in,
                              void* d_out, int out_size, void* d_ws, size_t ws_size,
                              hipStream_t stream) {
    const float* x  = (const float*)d_in[0];
    const int*   ei = (const int*)d_in[1];
    const float* Wm = (const float*)d_in[2];
    const float* bm = (const float*)d_in[3];
    const float* Wu = (const float*)d_in[4];
    const float* bu = (const float*)d_in[5];
    float* out = (float*)d_out;

    const int N_ = in_sizes[0] / D;     // 10000
    const int E_ = in_sizes[1] / 2;     // 640000
    const int NX = N_ * (D / 2);        // 640000 packed pairs

    int* deg       = (int*)d_ws;                  // N
    int* cursor    = deg + N_;                    // N
    int* row_start = cursor + N_;                 // N+1
    int* csr_col   = row_start + (N_ + 1);        // E
    uint32* xb     = (uint32*)(csr_col + E_);     // N*64
    float2* agg    = (float2*)(xb + NX);          // N*64 float2
    uint32* WTmb   = (uint32*)(agg + (size_t)N_ * 64);  // 64*128
    uint32* WTub   = WTmb + 64 * D;                      // 64*128

    hipMemsetAsync(deg, 0, 2 * (size_t)N_ * sizeof(int), stream);

    int pgrid = (max(E_, NX) + 255) / 256;
    k_prep<<<pgrid, 256, 0, stream>>>(x, ei, xb, deg, E_, NX);
    k_wprep<<<(64 * D + 255) / 256, 256, 0, stream>>>(Wm, Wu, WTmb, WTub);
    k_scan<<<1, 1024, 0, stream>>>(deg, row_start, N_);
    k_place<<<(E_ + 255) / 256, 256, 0, stream>>>(ei, row_start, cursor, csr_col, E_);

    k_gather<<<(N_ + 1) / 2, 256, 0, stream>>>(xb, row_start, csr_col, agg, N_);

    k_update<<<(N_ + 4 * NPW - 1) / (4 * NPW), 256, 0, stream>>>(
        agg, row_start, WTmb, bm, WTub, bu, out, N_);
}